// Round 1
// baseline (190.182 us; speedup 1.0000x reference)
//
#include <hip/hip_runtime.h>

typedef unsigned int u32;
typedef unsigned long long u64;
typedef __bf16 bf16x8 __attribute__((ext_vector_type(8)));
typedef float f32x4 __attribute__((ext_vector_type(4)));

#define N_TOK 4096   // B*S
#define IN_DIM 2048
#define OUT_DIM 4096
#define NCB 128      // codebooks C
#define NCENT 16     // centroids K
#define VLEN 16      // vec_len V
#define CK 2048      // NCB*NCENT  (GEMM inner dim)
#define KB 64        // K-blocks (CK/32)

static __device__ __forceinline__ unsigned short f2bf(float f) {
  u32 u = __float_as_uint(f);
  u = (u + 0x7FFFu + ((u >> 16) & 1u)) >> 16;  // round-to-nearest-even
  return (unsigned short)u;
}

// ---------------------------------------------------------------------------
// Kernel 1: Chebyshev argmin -> u8 index per (token, codebook).  (unchanged)
// ---------------------------------------------------------------------------
__global__ __launch_bounds__(256) void k_argmin_idx(
    const float* __restrict__ x,
    const float* __restrict__ cents,
    unsigned char* __restrict__ idx) {
  __shared__ float xs[16 * 260];
  __shared__ float cs[16 * 260];
  const int tid = threadIdx.x;
  const int n0 = blockIdx.x * 16;
  const int t = tid >> 4;
  const int cl = tid & 15;

  for (int g = 0; g < 4; ++g) {
    const int cg = blockIdx.y * 4 + g;
#pragma unroll
    for (int j = 0; j < 4; ++j) {
      const int fi = tid + 256 * j;
      const int row = fi >> 6;
      const int col = (fi & 63) * 4;
      *(float4*)(xs + row * 260 + col) =
          *(const float4*)(x + (size_t)(n0 + row) * IN_DIM + cg * 256 + col);
      *(float4*)(cs + row * 260 + col) =
          *(const float4*)(cents + ((size_t)cg * 16 + row) * 256 + col);
    }
    __syncthreads();

    float xr[16];
    const float* xv = xs + t * 260 + cl * 16;
#pragma unroll
    for (int q = 0; q < 4; ++q) {
      float4 tv = *(const float4*)(xv + q * 4);
      xr[q * 4 + 0] = tv.x; xr[q * 4 + 1] = tv.y;
      xr[q * 4 + 2] = tv.z; xr[q * 4 + 3] = tv.w;
    }
    const float* cb = cs + cl * 260;
    int bk = 0;
    float bd = 1e30f;
#pragma unroll
    for (int k = 0; k < NCENT; ++k) {
      float d = 0.f;
#pragma unroll
      for (int v = 0; v < VLEN; ++v) d = fmaxf(d, fabsf(xr[v] - cb[k * 16 + v]));
      if (d < bd) { bd = d; bk = k; }
    }
    idx[(size_t)(n0 + t) * NCB + cg * 16 + cl] = (unsigned char)bk;
    __syncthreads();
  }
}

// ---------------------------------------------------------------------------
// Kernel 2: LUT in MFMA B-fragment order (unchanged).
// Tile (tn=o>>4, kb=ck>>5) is 1KB contiguous; lane l = (o&15)+((ck&31)>>3)*16
// holds 8 bf16.
// ---------------------------------------------------------------------------
__global__ __launch_bounds__(256) void k_lut(const float* __restrict__ w,
                                             const float* __restrict__ cents,
                                             char* __restrict__ lutF) {
  const int tid = threadIdx.x;
  const int o0 = blockIdx.x * 64;
  const int cg = blockIdx.y;  // 8-codebook group 0..15
  const int p = tid >> 6;     // wave 0..3
  const int ol = tid & 63;
  const int o = o0 + ol;

  float acc[2][16];
#pragma unroll
  for (int cc = 0; cc < 2; ++cc)
#pragma unroll
    for (int k = 0; k < 16; ++k) acc[cc][k] = 0.f;

#pragma unroll
  for (int cc = 0; cc < 2; ++cc) {
    const int c = __builtin_amdgcn_readfirstlane(cg * 8 + p * 2 + cc);
    const float* cb = cents + (size_t)c * (NCENT * VLEN);  // scalar loads
#pragma unroll
    for (int v = 0; v < VLEN; ++v) {
      const float wv = w[(size_t)(c * 16 + v) * OUT_DIM + o];
#pragma unroll
      for (int k = 0; k < NCENT; ++k) acc[cc][k] = fmaf(cb[k * 16 + v], wv, acc[cc][k]);
    }
  }

#pragma unroll
  for (int cc = 0; cc < 2; ++cc) {
    const int c = cg * 8 + p * 2 + cc;
    u32 g[8];
#pragma unroll
    for (int kk = 0; kk < 8; ++kk)
      g[kk] = (u32)f2bf(acc[cc][2 * kk]) | ((u32)f2bf(acc[cc][2 * kk + 1]) << 16);
    char* base = lutF + ((size_t)(o >> 4) * KB + (c >> 1)) * 1024;
    const int l0 = (o & 15) + ((c & 1) * 2) * 16;
    *(uint4*)(base + l0 * 16)        = make_uint4(g[0], g[1], g[2], g[3]);
    *(uint4*)(base + (l0 + 16) * 16) = make_uint4(g[4], g[5], g[6], g[7]);
  }
}

// ---------------------------------------------------------------------------
// Kernel 3 (v2): fused one-hot GEMM, BARRIER-FREE main loop.
// The one-hot A fragment is built IN REGISTERS each k-block:
//   MFMA A layout: lane l holds A[m=l&15][kl=(l>>4)*8+j], j=0..7.
//   k-block t covers codebooks {2t, 2t+1}; lane constants:
//     hb = (l>>4)>>1  -> which codebook (kl>=16 half)
//     par8 = ((l>>4)&1)*8 -> which 8-slot half of the 16 centroids
//   frag is one-hot at j = iv - par8 when iv in [par8, par8+8):
//     uu = iv ^ par8; dbl = 0x3F80ull << ((uu&3)<<4);
//     lo64 = (uu&12)==0 ? dbl : 0;  hi64 = (uu&12)==4 ? dbl : 0;
// This deletes the LDS one-hot + BOTH per-k-block __syncthreads (the
// vmcnt(0)/lgkmcnt(0) barrier drains that capped MfmaUtil at ~15%).
// idx bytes staged once in LDS (stride 144 = 16B aligned, broadcast reads),
// read as one uint4 per mtile per 8-k-block chunk, bytes extracted by shift.
// B fragments double-buffered in registers from global (L2-resident via
// XCD swizzle: 1024 blocks = 8 XCDs x 128; each XCD owns 4 column slabs
// = 2MB of lutF < 4MB per-XCD L2).
// ---------------------------------------------------------------------------
__global__ __launch_bounds__(256) void k_gemm(
    const unsigned char* __restrict__ idx,  // [N_TOK][NCB] u8
    const char* __restrict__ Bf,            // fragment-ordered LUT
    const float* __restrict__ bias,
    float* __restrict__ out) {
  __shared__ unsigned char sIdx[128 * 144];  // 18KB, 16B-aligned rows
  const int tid = threadIdx.x;
  const int wave = tid >> 6;
  const int lane = tid & 63;

  // bijective XCD swizzle (1024 % 8 == 0): xcd = lin&7 owns by in [4*xcd, 4*xcd+4)
  const int lin = blockIdx.x + (int)(gridDim.x * blockIdx.y);
  const int slot = lin >> 3;
  const int bx = slot & 31;
  const int by = ((lin & 7) << 2) | (slot >> 5);
  const int m0 = bx * 128;
  const int n0 = by * 128;
  const int wm = (wave >> 1) * 64;
  const int wn = (wave & 1) * 64;

  // ---- stage sIdx (16KB payload, fully coalesced: idx rows are contiguous)
#pragma unroll
  for (int j = 0; j < 4; ++j) {
    const int u = tid + 256 * j;
    const int row = u >> 3;
    const int col = (u & 7) * 16;
    *(uint4*)(sIdx + row * 144 + col) =
        *(const uint4*)(idx + (size_t)(m0 + row) * NCB + col);
  }

  // per-lane constants for register one-hot build
  const int h = lane >> 4;
  const int hb = h >> 1;                  // codebook within k-block
  const u32 par8 = (u32)((h & 1) * 8);    // centroid-slot half
  const u32 sh0 = (u32)(hb * 8);          // byte-extract shift, even j
  const u32 sh1 = sh0 + 16;               // odd j
  const unsigned char* rb[4];
#pragma unroll
  for (int i = 0; i < 4; ++i) rb[i] = sIdx + (wm + i * 16 + (lane & 15)) * 144;

  // B-frag rolling offsets (32-bit, SGPR-base addressing), +=1024/k-block
  const int tb = (n0 >> 4) + (wn >> 4);
  u32 bo0 = (u32)tb * (KB * 1024) + (u32)lane * 16;
  u32 bo1 = bo0 + KB * 1024;
  u32 bo2 = bo1 + KB * 1024;
  u32 bo3 = bo2 + KB * 1024;

  __syncthreads();  // sIdx visible -- the ONLY barrier in this kernel

  uint4 Bc0 = *(const uint4*)(Bf + bo0);
  uint4 Bc1 = *(const uint4*)(Bf + bo1);
  uint4 Bc2 = *(const uint4*)(Bf + bo2);
  uint4 Bc3 = *(const uint4*)(Bf + bo3);
  bo0 += 1024; bo1 += 1024; bo2 += 1024; bo3 += 1024;

  f32x4 acc[4][4] = {};

  for (int q = 0; q < 8; ++q) {
    // idx chunk: 16 codebooks (8 k-blocks); same address for lane, lane+16,
    // lane+32, lane+48 -> LDS broadcast, conflict-free
    uint4 ch[4];
#pragma unroll
    for (int i = 0; i < 4; ++i) ch[i] = *(const uint4*)(rb[i] + q * 16);

#pragma unroll
    for (int j = 0; j < 8; ++j) {
      // prefetch next k-block's B (t=64 over-read lands in idx region:
      // allocated, values dead)
      uint4 Bn0 = *(const uint4*)(Bf + bo0);
      uint4 Bn1 = *(const uint4*)(Bf + bo1);
      uint4 Bn2 = *(const uint4*)(Bf + bo2);
      uint4 Bn3 = *(const uint4*)(Bf + bo3);
      bo0 += 1024; bo1 += 1024; bo2 += 1024; bo3 += 1024;

      // build 4 one-hot A fragments in registers (~11 VALU each)
      const u32 sh = (j & 1) ? sh1 : sh0;
      bf16x8 af[4];
#pragma unroll
      for (int i = 0; i < 4; ++i) {
        const u32 word = (j >> 1) == 0 ? ch[i].x
                       : (j >> 1) == 1 ? ch[i].y
                       : (j >> 1) == 2 ? ch[i].z
                                       : ch[i].w;
        const u32 iv = (word >> sh) & 0xFu;
        const u32 uu = iv ^ par8;
        const u64 dbl = 0x3F80ull << ((uu & 3u) << 4);
        const u64 lo = ((uu & 12u) == 0u) ? dbl : 0ull;
        const u64 hi = ((uu & 12u) == 4u) ? dbl : 0ull;
        uint4 f;
        f.x = (u32)lo; f.y = (u32)(lo >> 32);
        f.z = (u32)hi; f.w = (u32)(hi >> 32);
        af[i] = *(bf16x8*)&f;
      }

#pragma unroll
      for (int i = 0; i < 4; ++i) {
        acc[i][0] = __builtin_amdgcn_mfma_f32_16x16x32_bf16(
            af[i], *(const bf16x8*)&Bc0, acc[i][0], 0, 0, 0);
        acc[i][1] = __builtin_amdgcn_mfma_f32_16x16x32_bf16(
            af[i], *(const bf16x8*)&Bc1, acc[i][1], 0, 0, 0);
        acc[i][2] = __builtin_amdgcn_mfma_f32_16x16x32_bf16(
            af[i], *(const bf16x8*)&Bc2, acc[i][2], 0, 0, 0);
        acc[i][3] = __builtin_amdgcn_mfma_f32_16x16x32_bf16(
            af[i], *(const bf16x8*)&Bc3, acc[i][3], 0, 0, 0);
      }

      Bc0 = Bn0; Bc1 = Bn1; Bc2 = Bn2; Bc3 = Bn3;  // SSA-renamed by unroll
    }
  }

  // epilogue: D layout col=lane&15, row=(lane>>4)*4+r  [m89-verified]
  const int col = lane & 15;
  const int rbq = (lane >> 4) * 4;
  float bj[4];
#pragma unroll
  for (int j = 0; j < 4; ++j) bj[j] = bias[n0 + wn + j * 16 + col];
#pragma unroll
  for (int i = 0; i < 4; ++i) {
    const int gm = m0 + wm + i * 16 + rbq;
#pragma unroll
    for (int j = 0; j < 4; ++j) {
      const int gn = n0 + wn + j * 16 + col;
      float* op = out + (size_t)gm * OUT_DIM + gn;
#pragma unroll
      for (int r = 0; r < 4; ++r) op[(size_t)r * OUT_DIM] = acc[i][j][r] + bj[j];
    }
  }
}

// ---------------------------------------------------------------------------
extern "C" void kernel_launch(void* const* d_in, const int* in_sizes, int n_in,
                              void* d_out, int out_size, void* d_ws, size_t ws_size,
                              hipStream_t stream) {
  (void)in_sizes; (void)n_in; (void)out_size; (void)ws_size;
  const float* x      = (const float*)d_in[0];
  const float* weight = (const float*)d_in[1];
  const float* cents  = (const float*)d_in[2];
  const float* bias   = (const float*)d_in[3];
  // d_in[4] = vec_len (16), hardcoded

  char* lutF = (char*)d_ws;                                              // 16.8MB
  unsigned char* idx = (unsigned char*)d_ws + (size_t)OUT_DIM * CK * 2;  // 512KB
  float* out = (float*)d_out;

  k_argmin_idx<<<dim3(N_TOK / 16, 2), 256, 0, stream>>>(x, cents, idx);
  k_lut<<<dim3(OUT_DIM / 64, NCB / 8), 256, 0, stream>>>(weight, cents, lutF);
  k_gemm<<<dim3(N_TOK / 128, OUT_DIM / 128), 256, 0, stream>>>(idx, lutF, bias, out);
}